// Round 5
// baseline (281.431 us; speedup 1.0000x reference)
//
#include <hip/hip_runtime.h>
#include <hip/hip_fp16.h>

// ProtoNet distance matrix: out[n,k] = (alpha+1e-16)^2 * (||x_n||^2 + ||p_k||^2 - 2 x_n.p_k)
// x: [16384,1024] f32, p: [2048,1024] f32, alpha: [1] f32, out: [16384,2048] f32.
//
// v3: 256^2 8-phase schedule deepened to the template's exact steady state:
//  - 3 half-tiles in flight (boundary vmcnt(6), prologue stages 7 hts)
//  - stage stream s = p+7: q0->A-hi(t+1), q1->B-lo(t+2), q2->B-hi(t+2), q3->A-lo(t+2)
//    (each lands after its region's last ds_read + barrier; desk-verified)
//  - partial lgkmcnt(4) before the barrier in the 12-read phase q0 and 8-read q2
// Invariant: at boundary after tile t, issued hts = 4t+10, vmcnt(6) => ht<=4t+7
// landed = exactly tile t+1's data. vmcnt(0) only entering the last tile.

#define N_ROWS 16384
#define K_PROTO 2048
#define DIM 1024

#define BM 256
#define BN 256
#define BK 64
#define NT (DIM / BK)   // 16 K-tiles
#define NHT (4 * NT)    // 64 half-tiles

typedef _Float16 half8 __attribute__((ext_vector_type(8)));
typedef float f32x4 __attribute__((ext_vector_type(4)));

__device__ __forceinline__ void async_copy16(void* lds_dst, const void* g_src) {
    __builtin_amdgcn_global_load_lds(
        (const __attribute__((address_space(1))) void*)g_src,
        (__attribute__((address_space(3))) void*)lds_dst,
        16, 0, 0);
}

// ---------------- Pass 1: convert + row sum-of-squares (unchanged, verified) ----------------
__global__ __launch_bounds__(256) void convert_kernel(
    const float* __restrict__ x, const float* __restrict__ p,
    __half* __restrict__ xh, __half* __restrict__ ph,
    float* __restrict__ xsq, float* __restrict__ psq)
{
    int row = blockIdx.x;
    const float* src;
    __half* dst;
    float* sq;
    if (row < N_ROWS) {
        src = x + (size_t)row * DIM;
        dst = xh + (size_t)row * DIM;
        sq = xsq + row;
    } else {
        int r = row - N_ROWS;
        src = p + (size_t)r * DIM;
        dst = ph + (size_t)r * DIM;
        sq = psq + r;
    }
    int t = threadIdx.x;  // 256 threads x 4 floats = 1024
    float4 v = reinterpret_cast<const float4*>(src)[t];
    float s = v.x * v.x + v.y * v.y + v.z * v.z + v.w * v.w;

    union { __half2 h[2]; uint2 u; } pk;
    pk.h[0] = __floats2half2_rn(v.x, v.y);
    pk.h[1] = __floats2half2_rn(v.z, v.w);
    reinterpret_cast<uint2*>(dst)[t] = pk.u;

    #pragma unroll
    for (int off = 32; off > 0; off >>= 1) s += __shfl_down(s, off);
    __shared__ float red[4];
    if ((t & 63) == 0) red[t >> 6] = s;
    __syncthreads();
    if (t == 0) sq[0] = red[0] + red[1] + red[2] + red[3];
}

// ---------------- Pass 2: 256^2 8-phase fp16 MFMA GEMM ----------------
// grid = 64*8 = 512 blocks, 512 threads (8 waves 2Mx4N).
// LDS (dynamic, 128 KiB): buf b at b*65536: A[256][64]f16 @0, B[256][64]f16 @32768.

#define LDA(mo)                                                                      \
    do {                                                                             \
        _Pragma("unroll")                                                            \
        for (int m_ = 0; m_ < 4; ++m_) {                                             \
            const int row_ = wm * 128 + ((mo) + m_) * 16 + rr;                       \
            _Pragma("unroll")                                                        \
            for (int kk_ = 0; kk_ < 2; ++kk_)                                        \
                Af[m_][kk_] = *(const half8*)(Ab + row_ * 128 +                      \
                                   (((kk_ * 4 + lq) ^ (row_ & 7)) << 4));            \
        }                                                                            \
    } while (0)

#define LDB(n)                                                                       \
    do {                                                                             \
        const int row_ = wn * 64 + (n) * 16 + rr;                                    \
        _Pragma("unroll")                                                            \
        for (int kk_ = 0; kk_ < 2; ++kk_)                                            \
            Bf[n][kk_] = *(const half8*)(Bb + row_ * 128 +                           \
                               (((kk_ * 4 + lq) ^ (row_ & 7)) << 4));                \
    } while (0)

#define MMA8(mo, n0)                                                                 \
    do {                                                                             \
        _Pragma("unroll")                                                            \
        for (int m_ = 0; m_ < 4; ++m_)                                               \
            _Pragma("unroll")                                                        \
            for (int n_ = 0; n_ < 2; ++n_)                                           \
                _Pragma("unroll")                                                    \
                for (int kk_ = 0; kk_ < 2; ++kk_)                                    \
                    acc[(mo) + m_][(n0) + n_] =                                      \
                        __builtin_amdgcn_mfma_f32_16x16x32_f16(                      \
                            Af[m_][kk_], Bf[(n0) + n_][kk_],                         \
                            acc[(mo) + m_][(n0) + n_], 0, 0, 0);                     \
    } while (0)

#define PHASE_MID()                                                                  \
    __builtin_amdgcn_s_barrier();                                                    \
    asm volatile("s_waitcnt lgkmcnt(0)" ::: "memory");                               \
    __builtin_amdgcn_s_setprio(1)

#define PHASE_END()                                                                  \
    __builtin_amdgcn_s_setprio(0);                                                   \
    __builtin_amdgcn_s_barrier()

__global__ __launch_bounds__(512, 2) void gemm8_kernel(
    const __half* __restrict__ xh, const __half* __restrict__ ph,
    const float* __restrict__ xsq, const float* __restrict__ psq,
    const float* __restrict__ alpha, float* __restrict__ out)
{
    extern __shared__ char lds[];   // 131072 bytes

    const int tid = threadIdx.x;
    const int w = tid >> 6, lane = tid & 63;
    const int wm = w >> 2, wn = w & 3;       // 2 waves M x 4 waves N
    const int rr = lane & 15, lq = lane >> 4;

    // XCD-aware swizzle (nwg=512, 512%8==0 -> bijective simple form).
    const int bid = blockIdx.x;
    const int swz = (bid & 7) * 64 + (bid >> 3);
    const int bm = swz >> 3, bn = swz & 7;

    const __half* Abase = xh + (size_t)bm * BM * DIM;
    const __half* Bbase = ph + (size_t)bn * BN * DIM;

    f32x4 acc[8][4];
    #pragma unroll
    for (int m = 0; m < 8; ++m)
        #pragma unroll
        for (int n = 0; n < 4; ++n)
            acc[m][n] = (f32x4)0.0f;

    // half-tile s: tile T=s>>2, j=s&3: 0=B rows0-127, 1=B rows128-255,
    //                                  2=A rows0-127, 3=A rows128-255
    auto stage_ht = [&](int s) {
        if (s >= NHT) return;
        const int T = s >> 2, j = s & 3;
        char* buf = lds + (size_t)(T & 1) * 65536;
        const bool isA = (j >= 2);
        const int rowoff = (j & 1) << 7;                 // 0 or 128
        const __half* gb = isA ? Abase : Bbase;
        char* region = buf + (isA ? 0 : 32768) + rowoff * 128;
        #pragma unroll
        for (int i = 0; i < 2; ++i) {
            const int c = i * 512 + tid;                 // 0..1023
            const int r = c >> 3;                        // 0..127
            const int sl = (c & 7) ^ (r & 7);            // pre-swizzled source slot
            async_copy16(region + c * 16,
                         gb + (size_t)(rowoff + r) * DIM + T * BK + sl * 8);
        }
    };

    half8 Af[4][2], Bf[4][2];
    const char *Ab, *Bb;

    // prologue: stage ht 0..6 (tile0 all + tile1 B halves + tile1 A-lo);
    // vmcnt(6): 14 loads issued, <=6 outstanding -> ht0..3 (tile0) landed.
    #pragma unroll
    for (int s = 0; s < 7; ++s) stage_ht(s);
    asm volatile("s_waitcnt vmcnt(6)" ::: "memory");
    __builtin_amdgcn_s_barrier();

    for (int t = 0; t < NT; ++t) {
        const char* base = lds + (size_t)(t & 1) * 65536;
        Ab = base; Bb = base + 32768;
        const int p = t * 4;

        // q0: (mlo, nlo) — stages A-hi(t+1) [other buf]; 12 reads -> partial drain
        LDA(0); LDB(0); LDB(1);
        stage_ht(p + 7);
        asm volatile("s_waitcnt lgkmcnt(4)" ::: "memory");
        PHASE_MID();
        MMA8(0, 0);
        PHASE_END();

        // q1: (mlo, nhi) — stages B-lo(t+2) [cur buf; B-lo last read in q0]
        LDB(2); LDB(3);
        stage_ht(p + 8);
        PHASE_MID();
        MMA8(0, 2);
        PHASE_END();

        // q2: (mhi, nhi) — stages B-hi(t+2) [cur buf; B-hi last read in q1]
        LDA(4);
        stage_ht(p + 9);
        asm volatile("s_waitcnt lgkmcnt(4)" ::: "memory");
        PHASE_MID();
        MMA8(4, 2);
        PHASE_END();

        // q3: (mhi, nlo) — stages A-lo(t+2) [cur buf; A last read in q2]; boundary
        stage_ht(p + 10);
        __builtin_amdgcn_s_barrier();
        asm volatile("s_waitcnt lgkmcnt(0)" ::: "memory");
        __builtin_amdgcn_s_setprio(1);
        MMA8(4, 0);
        __builtin_amdgcn_s_setprio(0);
        if (t == NT - 2)
            asm volatile("s_waitcnt vmcnt(0)" ::: "memory");
        else if (t < NT - 2)
            asm volatile("s_waitcnt vmcnt(6)" ::: "memory");
        __builtin_amdgcn_s_barrier();
    }

    // epilogue: out = scale * (xsq[row] + psq[col] - 2*cross)
    const float a = alpha[0] + 1e-16f;
    const float scale = a * a;
    const int row0 = bm * BM + wm * 128 + lq * 4;
    const int col0 = bn * BN + wn * 64 + rr;
    #pragma unroll
    for (int n = 0; n < 4; ++n) {
        const int col = col0 + n * 16;
        const float pv = psq[col];
        #pragma unroll
        for (int m = 0; m < 8; ++m) {
            const int rbase = row0 + m * 16;
            #pragma unroll
            for (int r = 0; r < 4; ++r) {
                const int row = rbase + r;
                out[(size_t)row * K_PROTO + col] =
                    scale * (xsq[row] + pv - 2.0f * acc[m][n][r]);
            }
        }
    }
}

// ---------------- Fallback: direct fp32, no workspace (unchanged) ----------------
__global__ __launch_bounds__(256) void fallback_kernel(
    const float* __restrict__ x, const float* __restrict__ p,
    const float* __restrict__ alpha, float* __restrict__ out)
{
    __shared__ float xs[DIM];
    int n = blockIdx.x;
    int t = threadIdx.x;
    reinterpret_cast<float4*>(xs)[t] = reinterpret_cast<const float4*>(x + (size_t)n * DIM)[t];
    __syncthreads();
    const float a = alpha[0] + 1e-16f;
    const float scale = a * a;
    for (int j = 0; j < K_PROTO / 256; ++j) {
        int k = j * 256 + t;
        const float4* pr = reinterpret_cast<const float4*>(p + (size_t)k * DIM);
        float s = 0.0f;
        #pragma unroll 8
        for (int d4 = 0; d4 < DIM / 4; ++d4) {
            float4 pv = pr[d4];
            float dx = xs[d4 * 4 + 0] - pv.x;
            float dy = xs[d4 * 4 + 1] - pv.y;
            float dz = xs[d4 * 4 + 2] - pv.z;
            float dw = xs[d4 * 4 + 3] - pv.w;
            s += dx * dx + dy * dy + dz * dz + dw * dw;
        }
        out[(size_t)n * K_PROTO + k] = scale * s;
    }
}

extern "C" void kernel_launch(void* const* d_in, const int* in_sizes, int n_in,
                              void* d_out, int out_size, void* d_ws, size_t ws_size,
                              hipStream_t stream) {
    const float* x = (const float*)d_in[0];
    const float* p = (const float*)d_in[1];
    const float* alpha = (const float*)d_in[2];
    float* out = (float*)d_out;

    const size_t XH_BYTES = (size_t)N_ROWS * DIM * sizeof(__half);   // 32 MB
    const size_t PH_BYTES = (size_t)K_PROTO * DIM * sizeof(__half);  // 4 MB
    const size_t NEED = XH_BYTES + PH_BYTES +
                        (size_t)(N_ROWS + K_PROTO) * sizeof(float);

    if (ws_size < NEED) {
        fallback_kernel<<<dim3(N_ROWS), dim3(256), 0, stream>>>(x, p, alpha, out);
        return;
    }

    char* w = (char*)d_ws;
    __half* xh = (__half*)w;
    __half* ph = (__half*)(w + XH_BYTES);
    float* xsq = (float*)(w + XH_BYTES + PH_BYTES);
    float* psq = (float*)(w + XH_BYTES + PH_BYTES + N_ROWS * sizeof(float));

    convert_kernel<<<dim3(N_ROWS + K_PROTO), dim3(256), 0, stream>>>(
        x, p, xh, ph, xsq, psq);
    gemm8_kernel<<<dim3((N_ROWS / BM) * (K_PROTO / BN)), dim3(512), 131072, stream>>>(
        xh, ph, xsq, psq, alpha, out);
}

// Round 6
// 278.809 us; speedup vs baseline: 1.0094x; 1.0094x over previous
//
#include <hip/hip_runtime.h>
#include <hip/hip_fp16.h>

// ProtoNet distance matrix: out[n,k] = (alpha+1e-16)^2 * (||x_n||^2 + ||p_k||^2 - 2 x_n.p_k)
// x: [16384,1024] f32, p: [2048,1024] f32, alpha: [1] f32, out: [16384,2048] f32.
//
// v4: read-ahead pipelined 8-phase 256^2 GEMM. Each phase's LDS fragment reads
// are ISSUED one phase early (q0 pre-issues q1's B23; q1 pre-issues q2/q3's
// A-hi) so the ds_read drain overlaps the previous MFMA burst. Stage stream
// re-derived for read-ahead safety: q0->A-hi(t+1), q1->A-lo(t+2),
// q2->B-lo(t+2), q3->B-hi(t+2). Boundary vmcnt(6) (3 hts outstanding) lands
// exactly tile t+1's data. Waits: q0 lgkm(4), q1 lgkm(8), q2 lgkm(0).
// All region RAW/WAR hazards desk-verified (see analysis in session log).

#define N_ROWS 16384
#define K_PROTO 2048
#define DIM 1024

#define BM 256
#define BN 256
#define BK 64
#define NT (DIM / BK)   // 16 K-tiles
#define NHT (4 * NT)    // 64 half-tiles

typedef _Float16 half8 __attribute__((ext_vector_type(8)));
typedef float f32x4 __attribute__((ext_vector_type(4)));

__device__ __forceinline__ void async_copy16(void* lds_dst, const void* g_src) {
    __builtin_amdgcn_global_load_lds(
        (const __attribute__((address_space(1))) void*)g_src,
        (__attribute__((address_space(3))) void*)lds_dst,
        16, 0, 0);
}

// ---------------- Pass 1: convert + row sum-of-squares (unchanged, verified) ----------------
__global__ __launch_bounds__(256) void convert_kernel(
    const float* __restrict__ x, const float* __restrict__ p,
    __half* __restrict__ xh, __half* __restrict__ ph,
    float* __restrict__ xsq, float* __restrict__ psq)
{
    int row = blockIdx.x;
    const float* src;
    __half* dst;
    float* sq;
    if (row < N_ROWS) {
        src = x + (size_t)row * DIM;
        dst = xh + (size_t)row * DIM;
        sq = xsq + row;
    } else {
        int r = row - N_ROWS;
        src = p + (size_t)r * DIM;
        dst = ph + (size_t)r * DIM;
        sq = psq + r;
    }
    int t = threadIdx.x;  // 256 threads x 4 floats = 1024
    float4 v = reinterpret_cast<const float4*>(src)[t];
    float s = v.x * v.x + v.y * v.y + v.z * v.z + v.w * v.w;

    union { __half2 h[2]; uint2 u; } pk;
    pk.h[0] = __floats2half2_rn(v.x, v.y);
    pk.h[1] = __floats2half2_rn(v.z, v.w);
    reinterpret_cast<uint2*>(dst)[t] = pk.u;

    #pragma unroll
    for (int off = 32; off > 0; off >>= 1) s += __shfl_down(s, off);
    __shared__ float red[4];
    if ((t & 63) == 0) red[t >> 6] = s;
    __syncthreads();
    if (t == 0) sq[0] = red[0] + red[1] + red[2] + red[3];
}

// ---------------- Pass 2: read-ahead 8-phase 256^2 fp16 MFMA GEMM ----------------
// grid = 64*8 = 512 blocks, 512 threads (8 waves 2Mx4N).
// LDS (dynamic, 128 KiB): buf b at b*65536: A[256][64]f16 @0, B[256][64]f16 @32768.

#define LDA_(dst, mo)                                                                \
    do {                                                                             \
        _Pragma("unroll")                                                            \
        for (int m_ = 0; m_ < 4; ++m_) {                                             \
            const int row_ = wm * 128 + ((mo) + m_) * 16 + rr;                       \
            _Pragma("unroll")                                                        \
            for (int kk_ = 0; kk_ < 2; ++kk_)                                        \
                dst[m_][kk_] = *(const half8*)(Ab + row_ * 128 +                     \
                                   (((kk_ * 4 + lq) ^ (row_ & 7)) << 4));            \
        }                                                                            \
    } while (0)

#define LDB(n)                                                                       \
    do {                                                                             \
        const int row_ = wn * 64 + (n) * 16 + rr;                                    \
        _Pragma("unroll")                                                            \
        for (int kk_ = 0; kk_ < 2; ++kk_)                                            \
            Bf[n][kk_] = *(const half8*)(Bb + row_ * 128 +                           \
                               (((kk_ * 4 + lq) ^ (row_ & 7)) << 4));                \
    } while (0)

#define MMA8_(A_, mo, n0)                                                            \
    do {                                                                             \
        _Pragma("unroll")                                                            \
        for (int m_ = 0; m_ < 4; ++m_)                                               \
            _Pragma("unroll")                                                        \
            for (int n_ = 0; n_ < 2; ++n_)                                           \
                _Pragma("unroll")                                                    \
                for (int kk_ = 0; kk_ < 2; ++kk_)                                    \
                    acc[(mo) + m_][(n0) + n_] =                                      \
                        __builtin_amdgcn_mfma_f32_16x16x32_f16(                      \
                            A_[m_][kk_], Bf[(n0) + n_][kk_],                         \
                            acc[(mo) + m_][(n0) + n_], 0, 0, 0);                     \
    } while (0)

__global__ __launch_bounds__(512, 2) void gemm8_kernel(
    const __half* __restrict__ xh, const __half* __restrict__ ph,
    const float* __restrict__ xsq, const float* __restrict__ psq,
    const float* __restrict__ alpha, float* __restrict__ out)
{
    extern __shared__ char lds[];   // 131072 bytes

    const int tid = threadIdx.x;
    const int w = tid >> 6, lane = tid & 63;
    const int wm = w >> 2, wn = w & 3;       // 2 waves M x 4 waves N
    const int rr = lane & 15, lq = lane >> 4;

    // XCD-aware swizzle (nwg=512, 512%8==0 -> bijective simple form).
    const int bid = blockIdx.x;
    const int swz = (bid & 7) * 64 + (bid >> 3);
    const int bm = swz >> 3, bn = swz & 7;

    const __half* Abase = xh + (size_t)bm * BM * DIM;
    const __half* Bbase = ph + (size_t)bn * BN * DIM;

    f32x4 acc[8][4];
    #pragma unroll
    for (int m = 0; m < 8; ++m)
        #pragma unroll
        for (int n = 0; n < 4; ++n)
            acc[m][n] = (f32x4)0.0f;

    // half-tile stream (issue order): per tile t, slots are
    //   4t+0: A-lo(t)  4t+1: B-lo(t)  4t+2: B-hi(t)  4t+3: A-hi(t)
    // issued at: q1(t-2), q2(t-2), q3(t-2), q0(t-1)  [prologue covers t=0,1 partially]
    auto stage_ht = [&](int s) {
        if (s >= NHT) return;
        const int T = s >> 2, j = s & 3;   // j: 0=A-lo 1=B-lo 2=B-hi 3=A-hi
        char* buf = lds + (size_t)(T & 1) * 65536;
        const bool isA = (j == 0) | (j == 3);
        const int rowoff = ((j == 2) | (j == 3)) ? 128 : 0;
        const __half* gb = isA ? Abase : Bbase;
        char* region = buf + (isA ? 0 : 32768) + rowoff * 128;
        #pragma unroll
        for (int i = 0; i < 2; ++i) {
            const int c = i * 512 + tid;                 // 0..1023
            const int r = c >> 3;                        // 0..127
            const int sl = (c & 7) ^ (r & 7);            // pre-swizzled source slot
            async_copy16(region + c * 16,
                         gb + (size_t)(rowoff + r) * DIM + T * BK + sl * 8);
        }
    };

    half8 Af[4][2], Afh[4][2], Bf[4][2];
    const char *Ab, *Bb;

    // prologue: issue hts 0..6 = Al0,Bl0,Bh0,Ah0,Al1,Bl1,Bh1 (stream order);
    // vmcnt(6): 14 instrs issued, <=6 outstanding -> hts 0..3 landed (tile0 + Ah0).
    #pragma unroll
    for (int s = 0; s < 7; ++s) stage_ht(s);
    asm volatile("s_waitcnt vmcnt(6)" ::: "memory");
    __builtin_amdgcn_s_barrier();

    for (int t = 0; t < NT; ++t) {
        const char* base = lds + (size_t)(t & 1) * 65536;
        Ab = base; Bb = base + 32768;
        const int p4 = t * 4;

        // q0: reads A-lo + B01 (12) + read-ahead B23 (4); stages A-hi(t+1) [other buf]
        LDA_(Af, 0); LDB(0); LDB(1); LDB(2); LDB(3);
        stage_ht(p4 + 7);          // A-hi(t+1)
        __builtin_amdgcn_s_barrier();
        asm volatile("s_waitcnt lgkmcnt(4)" ::: "memory");  // allow B23-ra outstanding
        __builtin_amdgcn_s_setprio(1);
        MMA8_(Af, 0, 0);
        __builtin_amdgcn_s_setprio(0);
        __builtin_amdgcn_s_barrier();

        // q1: read-ahead A-hi (8); stages A-lo(t+2) [cur buf; A-lo drained in q0]
        LDA_(Afh, 4);
        stage_ht(p4 + 8);          // A-lo(t+2)
        __builtin_amdgcn_s_barrier();
        asm volatile("s_waitcnt lgkmcnt(8)" ::: "memory");  // B23 done; Afh-ra may remain
        __builtin_amdgcn_s_setprio(1);
        MMA8_(Af, 0, 2);
        __builtin_amdgcn_s_setprio(0);
        __builtin_amdgcn_s_barrier();

        // q2: no reads; stages B-lo(t+2) [all B reads drained before q1 MFMA]
        stage_ht(p4 + 9);          // B-lo(t+2)
        __builtin_amdgcn_s_barrier();
        asm volatile("s_waitcnt lgkmcnt(0)" ::: "memory");  // Afh ready
        __builtin_amdgcn_s_setprio(1);
        MMA8_(Afh, 4, 2);
        __builtin_amdgcn_s_setprio(0);
        __builtin_amdgcn_s_barrier();

        // q3: no reads; stages B-hi(t+2); boundary vmcnt
        stage_ht(p4 + 10);         // B-hi(t+2)
        __builtin_amdgcn_s_barrier();
        __builtin_amdgcn_s_setprio(1);
        MMA8_(Afh, 4, 0);
        __builtin_amdgcn_s_setprio(0);
        if (t == NT - 2)
            asm volatile("s_waitcnt vmcnt(0)" ::: "memory");
        else if (t < NT - 2)
            asm volatile("s_waitcnt vmcnt(6)" ::: "memory");
        __builtin_amdgcn_s_barrier();
    }

    // epilogue: out = scale * (xsq[row] + psq[col] - 2*cross); xsq via float4
    const float a = alpha[0] + 1e-16f;
    const float scale = a * a;
    const int row0 = bm * BM + wm * 128 + lq * 4;
    const int col0 = bn * BN + wn * 64 + rr;
    float4 xs4[8];
    #pragma unroll
    for (int m = 0; m < 8; ++m)
        xs4[m] = *reinterpret_cast<const float4*>(xsq + row0 + m * 16);
    #pragma unroll
    for (int n = 0; n < 4; ++n) {
        const int col = col0 + n * 16;
        const float pv = psq[col];
        #pragma unroll
        for (int m = 0; m < 8; ++m) {
            const int rbase = row0 + m * 16;
            #pragma unroll
            for (int r = 0; r < 4; ++r) {
                const float xv = (r == 0) ? xs4[m].x : (r == 1) ? xs4[m].y
                               : (r == 2) ? xs4[m].z : xs4[m].w;
                out[(size_t)(rbase + r) * K_PROTO + col] =
                    scale * (xv + pv - 2.0f * acc[m][n][r]);
            }
        }
    }
}

// ---------------- Fallback: direct fp32, no workspace (unchanged) ----------------
__global__ __launch_bounds__(256) void fallback_kernel(
    const float* __restrict__ x, const float* __restrict__ p,
    const float* __restrict__ alpha, float* __restrict__ out)
{
    __shared__ float xs[DIM];
    int n = blockIdx.x;
    int t = threadIdx.x;
    reinterpret_cast<float4*>(xs)[t] = reinterpret_cast<const float4*>(x + (size_t)n * DIM)[t];
    __syncthreads();
    const float a = alpha[0] + 1e-16f;
    const float scale = a * a;
    for (int j = 0; j < K_PROTO / 256; ++j) {
        int k = j * 256 + t;
        const float4* pr = reinterpret_cast<const float4*>(p + (size_t)k * DIM);
        float s = 0.0f;
        #pragma unroll 8
        for (int d4 = 0; d4 < DIM / 4; ++d4) {
            float4 pv = pr[d4];
            float dx = xs[d4 * 4 + 0] - pv.x;
            float dy = xs[d4 * 4 + 1] - pv.y;
            float dz = xs[d4 * 4 + 2] - pv.z;
            float dw = xs[d4 * 4 + 3] - pv.w;
            s += dx * dx + dy * dy + dz * dz + dw * dw;
        }
        out[(size_t)n * K_PROTO + k] = scale * s;
    }
}

extern "C" void kernel_launch(void* const* d_in, const int* in_sizes, int n_in,
                              void* d_out, int out_size, void* d_ws, size_t ws_size,
                              hipStream_t stream) {
    const float* x = (const float*)d_in[0];
    const float* p = (const float*)d_in[1];
    const float* alpha = (const float*)d_in[2];
    float* out = (float*)d_out;

    const size_t XH_BYTES = (size_t)N_ROWS * DIM * sizeof(__half);   // 32 MB
    const size_t PH_BYTES = (size_t)K_PROTO * DIM * sizeof(__half);  // 4 MB
    const size_t NEED = XH_BYTES + PH_BYTES +
                        (size_t)(N_ROWS + K_PROTO) * sizeof(float);

    if (ws_size < NEED) {
        fallback_kernel<<<dim3(N_ROWS), dim3(256), 0, stream>>>(x, p, alpha, out);
        return;
    }

    char* w = (char*)d_ws;
    __half* xh = (__half*)w;
    __half* ph = (__half*)(w + XH_BYTES);
    float* xsq = (float*)(w + XH_BYTES + PH_BYTES);
    float* psq = (float*)(w + XH_BYTES + PH_BYTES + N_ROWS * sizeof(float));

    convert_kernel<<<dim3(N_ROWS + K_PROTO), dim3(256), 0, stream>>>(
        x, p, xh, ph, xsq, psq);
    gemm8_kernel<<<dim3((N_ROWS / BM) * (K_PROTO / BN)), dim3(512), 131072, stream>>>(
        xh, ph, xsq, psq, alpha, out);
}